// Round 1
// baseline (11568.314 us; speedup 1.0000x reference)
//
#include <hip/hip_runtime.h>
#include <math.h>

#define NNODES 100000
#define NEDGES 3200000
#define NFEAT  512
#define NHID   256
#define NCLASS 40

// ---------------- GEMM1: h0 = x @ W1 + b1   [N,512] x [512,256] -------------
__global__ __launch_bounds__(256) void gemm1_kernel(
    const float* __restrict__ x, const float* __restrict__ W1,
    const float* __restrict__ b1, float* __restrict__ h0)
{
    __shared__ float As[16][64];   // [k][m]
    __shared__ float Bs[16][64];   // [k][n]
    const int t = threadIdx.x;
    const int row0 = blockIdx.x * 64;
    const int col0 = blockIdx.y * 64;
    const int tm = (t >> 4) * 4;        // 0..60
    const int tn = (t & 15) * 4;        // 0..60
    const int am = t >> 2, ak = (t & 3) * 4;
    const int bk = t >> 4, bn = (t & 15) * 4;
    float acc[4][4] = {};
    for (int k0 = 0; k0 < NFEAT; k0 += 16) {
        float4 av = make_float4(0.f, 0.f, 0.f, 0.f);
        const int arow = row0 + am;
        if (arow < NNODES)
            av = *(const float4*)(x + (size_t)arow * NFEAT + k0 + ak);
        As[ak + 0][am] = av.x; As[ak + 1][am] = av.y;
        As[ak + 2][am] = av.z; As[ak + 3][am] = av.w;
        const float4 bv = *(const float4*)(W1 + (size_t)(k0 + bk) * NHID + col0 + bn);
        *(float4*)&Bs[bk][bn] = bv;
        __syncthreads();
        #pragma unroll
        for (int k = 0; k < 16; ++k) {
            const float4 a4 = *(const float4*)&As[k][tm];
            const float4 b4 = *(const float4*)&Bs[k][tn];
            const float av_[4] = {a4.x, a4.y, a4.z, a4.w};
            const float bv_[4] = {b4.x, b4.y, b4.z, b4.w};
            #pragma unroll
            for (int i = 0; i < 4; ++i)
                #pragma unroll
                for (int j = 0; j < 4; ++j)
                    acc[i][j] += av_[i] * bv_[j];
        }
        __syncthreads();
    }
    #pragma unroll
    for (int i = 0; i < 4; ++i) {
        const int r = row0 + tm + i;
        if (r < NNODES) {
            float4 o;
            o.x = acc[i][0] + b1[col0 + tn + 0];
            o.y = acc[i][1] + b1[col0 + tn + 1];
            o.z = acc[i][2] + b1[col0 + tn + 2];
            o.w = acc[i][3] + b1[col0 + tn + 3];
            *(float4*)(h0 + (size_t)r * NHID + col0 + tn) = o;
        }
    }
}

// ---------------- zero fill ------------------------------------------------
__global__ __launch_bounds__(256) void zero_kernel(float4* __restrict__ p, int n4)
{
    const int i = blockIdx.x * 256 + threadIdx.x;
    if (i < n4) p[i] = make_float4(0.f, 0.f, 0.f, 0.f);
}

// ---------------- SpMM1: h1[dst] += w * h0[src]  (256 feats, wave/edge) ----
__global__ __launch_bounds__(256) void spmm1_kernel(
    const int* __restrict__ ei, const float* __restrict__ ew,
    const float* __restrict__ h0, float* __restrict__ h1)
{
    const int e = blockIdx.x * 4 + (threadIdx.x >> 6);
    const int lane = threadIdx.x & 63;
    const int dst = ei[e];
    const int src = ei[NEDGES + e];
    const float w = ew[e];
    const float4 v = *(const float4*)(h0 + (size_t)src * NHID + lane * 4);
    float* o = h1 + (size_t)dst * NHID + lane * 4;
    atomicAdd(o + 0, v.x * w);
    atomicAdd(o + 1, v.y * w);
    atomicAdd(o + 2, v.z * w);
    atomicAdd(o + 3, v.w * w);
}

// ---------------- GEMM2: h2 = relu(h1) @ W2 + b2   [N,256] x [256,40] ------
__global__ __launch_bounds__(256) void gemm2_kernel(
    const float* __restrict__ h1, const float* __restrict__ W2,
    const float* __restrict__ b2, float* __restrict__ h2)
{
    __shared__ float Bs[NHID * NCLASS]; // full W2: 256*40 floats = 40 KB
    __shared__ float As[64][33];        // 64 rows x 32 k, +1 pad = 8.4 KB
    const int t = threadIdx.x;
    const int row0 = blockIdx.x * 64;
    for (int i = t; i < NHID * NCLASS; i += 256) Bs[i] = W2[i];
    const int r  = t & 63;
    const int cg = (t >> 6) * 10;       // 4 col-groups of 10
    const int am = t >> 2, ak = (t & 3) * 8;
    float acc[10] = {};
    for (int k0 = 0; k0 < NHID; k0 += 32) {
        __syncthreads();                 // Bs ready (iter 0); As reads done (iter>0)
        float4 v0 = make_float4(0.f,0.f,0.f,0.f), v1 = v0;
        const int arow = row0 + am;
        if (arow < NNODES) {
            v0 = *(const float4*)(h1 + (size_t)arow * NHID + k0 + ak);
            v1 = *(const float4*)(h1 + (size_t)arow * NHID + k0 + ak + 4);
        }
        As[am][ak + 0] = fmaxf(v0.x, 0.f); As[am][ak + 1] = fmaxf(v0.y, 0.f);
        As[am][ak + 2] = fmaxf(v0.z, 0.f); As[am][ak + 3] = fmaxf(v0.w, 0.f);
        As[am][ak + 4] = fmaxf(v1.x, 0.f); As[am][ak + 5] = fmaxf(v1.y, 0.f);
        As[am][ak + 6] = fmaxf(v1.z, 0.f); As[am][ak + 7] = fmaxf(v1.w, 0.f);
        __syncthreads();
        #pragma unroll
        for (int k = 0; k < 32; ++k) {
            const float a = As[r][k];
            #pragma unroll
            for (int j = 0; j < 10; ++j)
                acc[j] += a * Bs[(k0 + k) * NCLASS + cg + j];
        }
    }
    const int arow = row0 + r;
    if (arow < NNODES) {
        #pragma unroll
        for (int j = 0; j < 10; ++j)
            h2[(size_t)arow * NCLASS + cg + j] = acc[j] + b2[cg + j];
    }
}

// ---------------- SpMM2: out[dst] += w * h2[src]  (40 feats, thread/elem) --
__global__ __launch_bounds__(256) void spmm2_kernel(
    const int* __restrict__ ei, const float* __restrict__ ew,
    const float* __restrict__ h2, float* __restrict__ out)
{
    const int idx = blockIdx.x * 256 + threadIdx.x;   // E*40 = 128M total
    const int e = idx / NCLASS;
    const int f = idx - e * NCLASS;
    const int dst = ei[e];
    const int src = ei[NEDGES + e];
    atomicAdd(out + (size_t)dst * NCLASS + f, h2[(size_t)src * NCLASS + f] * ew[e]);
}

// ---------------- row log-softmax over 40 classes (wave/row) ---------------
__global__ __launch_bounds__(256) void logsoftmax_kernel(float* __restrict__ out)
{
    const int row  = blockIdx.x * 4 + (threadIdx.x >> 6);
    const int lane = threadIdx.x & 63;
    float v = -INFINITY;
    if (lane < NCLASS) v = out[(size_t)row * NCLASS + lane];
    float m = v;
    #pragma unroll
    for (int o = 32; o >= 1; o >>= 1) m = fmaxf(m, __shfl_xor(m, o));
    float ex = (lane < NCLASS) ? expf(v - m) : 0.f;
    float s = ex;
    #pragma unroll
    for (int o = 32; o >= 1; o >>= 1) s += __shfl_xor(s, o);
    if (lane < NCLASS) out[(size_t)row * NCLASS + lane] = v - m - logf(s);
}

extern "C" void kernel_launch(void* const* d_in, const int* in_sizes, int n_in,
                              void* d_out, int out_size, void* d_ws, size_t ws_size,
                              hipStream_t stream)
{
    const float* x  = (const float*)d_in[0];
    const int*   ei = (const int*)d_in[1];   // [2,E]: rows(dst) then cols(src)
    const float* ew = (const float*)d_in[2];
    const float* W1 = (const float*)d_in[3];
    const float* b1 = (const float*)d_in[4];
    const float* W2 = (const float*)d_in[5];
    const float* b2 = (const float*)d_in[6];
    float* out = (float*)d_out;

    float* h0 = (float*)d_ws;                         // [N, 256]  102.4 MB
    float* h1 = h0 + (size_t)NNODES * NHID;           // [N, 256]  102.4 MB
    float* h2 = h1 + (size_t)NNODES * NHID;           // [N, 40]   16 MB

    // 1. h0 = x @ W1 + b1
    gemm1_kernel<<<dim3((NNODES + 63) / 64, NHID / 64), 256, 0, stream>>>(x, W1, b1, h0);
    // 2. h1 = 0; h1 = spmm(h0)
    zero_kernel<<<(NNODES * NHID / 4 + 255) / 256, 256, 0, stream>>>(
        (float4*)h1, NNODES * NHID / 4);
    spmm1_kernel<<<NEDGES / 4, 256, 0, stream>>>(ei, ew, h0, h1);
    // 3. h2 = relu(h1) @ W2 + b2
    gemm2_kernel<<<(NNODES + 63) / 64, 256, 0, stream>>>(h1, W2, b2, h2);
    // 4. out = 0; out = spmm(h2)
    zero_kernel<<<(NNODES * NCLASS / 4 + 255) / 256, 256, 0, stream>>>(
        (float4*)out, NNODES * NCLASS / 4);
    spmm2_kernel<<<(NEDGES / 256) * NCLASS, 256, 0, stream>>>(ei, ew, h2, out);
    // 5. log-softmax rows in place
    logsoftmax_kernel<<<NNODES / 4, 256, 0, stream>>>(out);
}

// Round 2
// 1442.666 us; speedup vs baseline: 8.0187x; 8.0187x over previous
//
#include <hip/hip_runtime.h>
#include <math.h>

#define NNODES 100000
#define NEDGES 3200000
#define NFEAT  512
#define NHID   256
#define NCLASS 40
#define NB_SCAN 98              // ceil(NNODES / 1024)

// ======================= GEMM1: h0 = x @ W1 + b1 ===========================
__global__ __launch_bounds__(256) void gemm1_kernel(
    const float* __restrict__ x, const float* __restrict__ W1,
    const float* __restrict__ b1, float* __restrict__ h0)
{
    __shared__ float As[16][64];   // [k][m]
    __shared__ float Bs[16][64];   // [k][n]
    const int t = threadIdx.x;
    const int row0 = blockIdx.x * 64;
    const int col0 = blockIdx.y * 64;
    const int tm = (t >> 4) * 4;
    const int tn = (t & 15) * 4;
    const int am = t >> 2, ak = (t & 3) * 4;
    const int bk = t >> 4, bn = (t & 15) * 4;
    float acc[4][4] = {};
    for (int k0 = 0; k0 < NFEAT; k0 += 16) {
        float4 av = make_float4(0.f, 0.f, 0.f, 0.f);
        const int arow = row0 + am;
        if (arow < NNODES)
            av = *(const float4*)(x + (size_t)arow * NFEAT + k0 + ak);
        As[ak + 0][am] = av.x; As[ak + 1][am] = av.y;
        As[ak + 2][am] = av.z; As[ak + 3][am] = av.w;
        const float4 bv = *(const float4*)(W1 + (size_t)(k0 + bk) * NHID + col0 + bn);
        *(float4*)&Bs[bk][bn] = bv;
        __syncthreads();
        #pragma unroll
        for (int k = 0; k < 16; ++k) {
            const float4 a4 = *(const float4*)&As[k][tm];
            const float4 b4 = *(const float4*)&Bs[k][tn];
            const float av_[4] = {a4.x, a4.y, a4.z, a4.w};
            const float bv_[4] = {b4.x, b4.y, b4.z, b4.w};
            #pragma unroll
            for (int i = 0; i < 4; ++i)
                #pragma unroll
                for (int j = 0; j < 4; ++j)
                    acc[i][j] += av_[i] * bv_[j];
        }
        __syncthreads();
    }
    #pragma unroll
    for (int i = 0; i < 4; ++i) {
        const int r = row0 + tm + i;
        if (r < NNODES) {
            float4 o;
            o.x = acc[i][0] + b1[col0 + tn + 0];
            o.y = acc[i][1] + b1[col0 + tn + 1];
            o.z = acc[i][2] + b1[col0 + tn + 2];
            o.w = acc[i][3] + b1[col0 + tn + 3];
            *(float4*)(h0 + (size_t)r * NHID + col0 + tn) = o;
        }
    }
}

// ======================= GEMM2: h2 = A @ W2 + b2 (A = h1 or relu(h1)) ======
template <bool RELU>
__global__ __launch_bounds__(256) void gemm2_kernel(
    const float* __restrict__ h1, const float* __restrict__ W2,
    const float* __restrict__ b2, float* __restrict__ h2)
{
    __shared__ float Bs[NHID * NCLASS]; // full W2: 40 KB
    __shared__ float As[64][33];
    const int t = threadIdx.x;
    const int row0 = blockIdx.x * 64;
    for (int i = t; i < NHID * NCLASS; i += 256) Bs[i] = W2[i];
    const int r  = t & 63;
    const int cg = (t >> 6) * 10;
    const int am = t >> 2, ak = (t & 3) * 8;
    float acc[10] = {};
    for (int k0 = 0; k0 < NHID; k0 += 32) {
        __syncthreads();
        float4 v0 = make_float4(0.f,0.f,0.f,0.f), v1 = v0;
        const int arow = row0 + am;
        if (arow < NNODES) {
            v0 = *(const float4*)(h1 + (size_t)arow * NHID + k0 + ak);
            v1 = *(const float4*)(h1 + (size_t)arow * NHID + k0 + ak + 4);
        }
        if (RELU) {
            v0.x = fmaxf(v0.x, 0.f); v0.y = fmaxf(v0.y, 0.f);
            v0.z = fmaxf(v0.z, 0.f); v0.w = fmaxf(v0.w, 0.f);
            v1.x = fmaxf(v1.x, 0.f); v1.y = fmaxf(v1.y, 0.f);
            v1.z = fmaxf(v1.z, 0.f); v1.w = fmaxf(v1.w, 0.f);
        }
        As[am][ak + 0] = v0.x; As[am][ak + 1] = v0.y;
        As[am][ak + 2] = v0.z; As[am][ak + 3] = v0.w;
        As[am][ak + 4] = v1.x; As[am][ak + 5] = v1.y;
        As[am][ak + 6] = v1.z; As[am][ak + 7] = v1.w;
        __syncthreads();
        #pragma unroll
        for (int k = 0; k < 32; ++k) {
            const float a = As[r][k];
            #pragma unroll
            for (int j = 0; j < 10; ++j)
                acc[j] += a * Bs[(k0 + k) * NCLASS + cg + j];
        }
    }
    const int arow = row0 + r;
    if (arow < NNODES) {
        #pragma unroll
        for (int j = 0; j < 10; ++j)
            h2[(size_t)arow * NCLASS + cg + j] = acc[j] + b2[cg + j];
    }
}

// ======================= CSR build =========================================
__global__ __launch_bounds__(256) void zero_int_kernel(int* __restrict__ p, int n)
{
    const int i = blockIdx.x * 256 + threadIdx.x;
    if (i < n) p[i] = 0;
}

__global__ __launch_bounds__(256) void hist_kernel(
    const int* __restrict__ ei, int* __restrict__ deg)
{
    const int e = blockIdx.x * 256 + threadIdx.x;
    if (e < NEDGES) atomicAdd(&deg[ei[e]], 1);
}

// block: 256 thr x 4 elems = 1024 per block; exclusive scan within block
__global__ __launch_bounds__(256) void scan1_kernel(
    const int* __restrict__ deg, int* __restrict__ rowptr, int* __restrict__ bsum)
{
    __shared__ int s[256];
    const int b = blockIdx.x, t = threadIdx.x;
    const int i0 = b * 1024 + t * 4;
    int v[4];
    #pragma unroll
    for (int j = 0; j < 4; ++j) v[j] = (i0 + j < NNODES) ? deg[i0 + j] : 0;
    const int mysum = v[0] + v[1] + v[2] + v[3];
    s[t] = mysum;
    __syncthreads();
    for (int o = 1; o < 256; o <<= 1) {
        const int u = (t >= o) ? s[t - o] : 0;
        __syncthreads();
        s[t] += u;
        __syncthreads();
    }
    int run = s[t] - mysum;   // exclusive prefix for this thread
    #pragma unroll
    for (int j = 0; j < 4; ++j) {
        if (i0 + j < NNODES) rowptr[i0 + j] = run;
        run += v[j];
    }
    if (t == 255) bsum[b] = s[255];
}

__global__ __launch_bounds__(128) void scan2_kernel(int* __restrict__ bsum)
{
    __shared__ int s[128];
    const int t = threadIdx.x;
    const int v = (t < NB_SCAN) ? bsum[t] : 0;
    s[t] = v;
    __syncthreads();
    for (int o = 1; o < 128; o <<= 1) {
        const int u = (t >= o) ? s[t - o] : 0;
        __syncthreads();
        s[t] += u;
        __syncthreads();
    }
    if (t < NB_SCAN) bsum[t] = s[t] - v;   // exclusive
}

__global__ __launch_bounds__(256) void scan3_kernel(
    int* __restrict__ rowptr, int* __restrict__ cursor, const int* __restrict__ bsum)
{
    const int b = blockIdx.x, t = threadIdx.x;
    const int i0 = b * 1024 + t * 4;
    const int off = bsum[b];
    #pragma unroll
    for (int j = 0; j < 4; ++j) {
        const int i = i0 + j;
        if (i < NNODES) {
            const int r = rowptr[i] + off;
            rowptr[i] = r;
            cursor[i] = r;
        }
    }
    if (b == 0 && t == 0) rowptr[NNODES] = NEDGES;
}

__global__ __launch_bounds__(256) void scatter_kernel(
    const int* __restrict__ ei, const float* __restrict__ ew,
    int* __restrict__ cursor, int2* __restrict__ pairs)
{
    const int e = blockIdx.x * 256 + threadIdx.x;
    if (e < NEDGES) {
        const int dst = ei[e];
        const int p = atomicAdd(&cursor[dst], 1);
        int2 pr;
        pr.x = ei[NEDGES + e];
        pr.y = __float_as_int(ew[e]);
        pairs[p] = pr;
    }
}

// ======================= CSR SpMM1 (+fused ReLU): wave per dst row =========
__global__ __launch_bounds__(256) void spmm1_csr_kernel(
    const int* __restrict__ rowptr, const int2* __restrict__ pairs,
    const float* __restrict__ h0, float* __restrict__ h1)
{
    const int dst  = blockIdx.x * 4 + (threadIdx.x >> 6);
    const int lane = threadIdx.x & 63;
    if (dst >= NNODES) return;
    const int beg = rowptr[dst], end = rowptr[dst + 1];
    float4 a0 = make_float4(0.f, 0.f, 0.f, 0.f);
    float4 a1 = make_float4(0.f, 0.f, 0.f, 0.f);
    int j = beg;
    for (; j + 1 < end; j += 2) {
        const int2 p0 = pairs[j];
        const int2 p1 = pairs[j + 1];
        const float4 v0 = *(const float4*)(h0 + (size_t)p0.x * NHID + lane * 4);
        const float4 v1 = *(const float4*)(h0 + (size_t)p1.x * NHID + lane * 4);
        const float w0 = __int_as_float(p0.y), w1 = __int_as_float(p1.y);
        a0.x = fmaf(v0.x, w0, a0.x); a0.y = fmaf(v0.y, w0, a0.y);
        a0.z = fmaf(v0.z, w0, a0.z); a0.w = fmaf(v0.w, w0, a0.w);
        a1.x = fmaf(v1.x, w1, a1.x); a1.y = fmaf(v1.y, w1, a1.y);
        a1.z = fmaf(v1.z, w1, a1.z); a1.w = fmaf(v1.w, w1, a1.w);
    }
    if (j < end) {
        const int2 p0 = pairs[j];
        const float4 v0 = *(const float4*)(h0 + (size_t)p0.x * NHID + lane * 4);
        const float w0 = __int_as_float(p0.y);
        a0.x = fmaf(v0.x, w0, a0.x); a0.y = fmaf(v0.y, w0, a0.y);
        a0.z = fmaf(v0.z, w0, a0.z); a0.w = fmaf(v0.w, w0, a0.w);
    }
    float4 o;
    o.x = fmaxf(a0.x + a1.x, 0.f);
    o.y = fmaxf(a0.y + a1.y, 0.f);
    o.z = fmaxf(a0.z + a1.z, 0.f);
    o.w = fmaxf(a0.w + a1.w, 0.f);
    *(float4*)(h1 + (size_t)dst * NHID + lane * 4) = o;
}

// ======================= CSR SpMM2 + fused log-softmax: wave per dst =======
__global__ __launch_bounds__(256) void spmm2_csr_kernel(
    const int* __restrict__ rowptr, const int2* __restrict__ pairs,
    const float* __restrict__ h2, float* __restrict__ out)
{
    const int dst  = blockIdx.x * 4 + (threadIdx.x >> 6);
    const int lane = threadIdx.x & 63;
    if (dst >= NNODES) return;
    const int beg = rowptr[dst], end = rowptr[dst + 1];
    float a0 = 0.f, a1 = 0.f;
    int j = beg;
    for (; j + 1 < end; j += 2) {
        const int2 p0 = pairs[j];
        const int2 p1 = pairs[j + 1];
        float v0 = 0.f, v1 = 0.f;
        if (lane < NCLASS) {
            v0 = h2[(size_t)p0.x * NCLASS + lane];
            v1 = h2[(size_t)p1.x * NCLASS + lane];
        }
        a0 = fmaf(v0, __int_as_float(p0.y), a0);
        a1 = fmaf(v1, __int_as_float(p1.y), a1);
    }
    if (j < end) {
        const int2 p0 = pairs[j];
        float v0 = 0.f;
        if (lane < NCLASS) v0 = h2[(size_t)p0.x * NCLASS + lane];
        a0 = fmaf(v0, __int_as_float(p0.y), a0);
    }
    const float acc = a0 + a1;
    // fused row log-softmax across lanes 0..39
    float val = (lane < NCLASS) ? acc : -INFINITY;
    float m = val;
    #pragma unroll
    for (int o = 32; o >= 1; o >>= 1) m = fmaxf(m, __shfl_xor(m, o));
    float ex = (lane < NCLASS) ? expf(val - m) : 0.f;
    float s = ex;
    #pragma unroll
    for (int o = 32; o >= 1; o >>= 1) s += __shfl_xor(s, o);
    if (lane < NCLASS) out[(size_t)dst * NCLASS + lane] = val - m - logf(s);
}

// ======================= fallback (round-1 atomic path) ====================
__global__ __launch_bounds__(256) void zero_kernel(float4* __restrict__ p, int n4)
{
    const int i = blockIdx.x * 256 + threadIdx.x;
    if (i < n4) p[i] = make_float4(0.f, 0.f, 0.f, 0.f);
}

__global__ __launch_bounds__(256) void spmm1_atomic_kernel(
    const int* __restrict__ ei, const float* __restrict__ ew,
    const float* __restrict__ h0, float* __restrict__ h1)
{
    const int e = blockIdx.x * 4 + (threadIdx.x >> 6);
    const int lane = threadIdx.x & 63;
    const int dst = ei[e];
    const int src = ei[NEDGES + e];
    const float w = ew[e];
    const float4 v = *(const float4*)(h0 + (size_t)src * NHID + lane * 4);
    float* o = h1 + (size_t)dst * NHID + lane * 4;
    atomicAdd(o + 0, v.x * w);
    atomicAdd(o + 1, v.y * w);
    atomicAdd(o + 2, v.z * w);
    atomicAdd(o + 3, v.w * w);
}

__global__ __launch_bounds__(256) void spmm2_atomic_kernel(
    const int* __restrict__ ei, const float* __restrict__ ew,
    const float* __restrict__ h2, float* __restrict__ out)
{
    const int idx = blockIdx.x * 256 + threadIdx.x;
    const int e = idx / NCLASS;
    const int f = idx - e * NCLASS;
    const int dst = ei[e];
    const int src = ei[NEDGES + e];
    atomicAdd(out + (size_t)dst * NCLASS + f, h2[(size_t)src * NCLASS + f] * ew[e]);
}

__global__ __launch_bounds__(256) void logsoftmax_kernel(float* __restrict__ out)
{
    const int row  = blockIdx.x * 4 + (threadIdx.x >> 6);
    const int lane = threadIdx.x & 63;
    float v = -INFINITY;
    if (lane < NCLASS) v = out[(size_t)row * NCLASS + lane];
    float m = v;
    #pragma unroll
    for (int o = 32; o >= 1; o >>= 1) m = fmaxf(m, __shfl_xor(m, o));
    float ex = (lane < NCLASS) ? expf(v - m) : 0.f;
    float s = ex;
    #pragma unroll
    for (int o = 32; o >= 1; o >>= 1) s += __shfl_xor(s, o);
    if (lane < NCLASS) out[(size_t)row * NCLASS + lane] = v - m - logf(s);
}

// ======================= launch ============================================
extern "C" void kernel_launch(void* const* d_in, const int* in_sizes, int n_in,
                              void* d_out, int out_size, void* d_ws, size_t ws_size,
                              hipStream_t stream)
{
    const float* x  = (const float*)d_in[0];
    const int*   ei = (const int*)d_in[1];   // [2,E]: dst row then src row
    const float* ew = (const float*)d_in[2];
    const float* W1 = (const float*)d_in[3];
    const float* b1 = (const float*)d_in[4];
    const float* W2 = (const float*)d_in[5];
    const float* b2 = (const float*)d_in[6];
    float* out = (float*)d_out;

    char* ws = (char*)d_ws;
    const size_t H_BYTES = (size_t)NNODES * NHID * 4;        // 102,400,000
    float* h0 = (float*)(ws);
    float* h1 = (float*)(ws + H_BYTES);

    // CSR region after h1
    size_t off = 2 * H_BYTES;
    int2* pairs  = (int2*)(ws + off);  off += (size_t)NEDGES * 8;      // 25.6 MB
    int* rowptr  = (int*)(ws + off);   off += ((size_t)(NNODES + 1) * 4 + 15) & ~15ull;
    int* cursor  = (int*)(ws + off);   off += ((size_t)NNODES * 4 + 15) & ~15ull;
    int* bsum    = (int*)(ws + off);   off += 512;
    const size_t CSR_NEED = off;
    float* h2 = (float*)(ws);          // aliases h0 (dead after spmm1)

    // 1. h0 = x @ W1 + b1
    gemm1_kernel<<<dim3((NNODES + 63) / 64, NHID / 64), 256, 0, stream>>>(x, W1, b1, h0);

    if (ws_size >= CSR_NEED) {
        // 2. build CSR of the destination-grouped edge list
        zero_int_kernel<<<(NNODES + 255) / 256, 256, 0, stream>>>(cursor, NNODES);
        hist_kernel<<<(NEDGES + 255) / 256, 256, 0, stream>>>(ei, cursor);
        scan1_kernel<<<NB_SCAN, 256, 0, stream>>>(cursor, rowptr, bsum);
        scan2_kernel<<<1, 128, 0, stream>>>(bsum);
        scan3_kernel<<<NB_SCAN, 256, 0, stream>>>(rowptr, cursor, bsum);
        scatter_kernel<<<(NEDGES + 255) / 256, 256, 0, stream>>>(ei, ew, cursor, pairs);
        // 3. h1 = relu(spmm(h0))  — gather, no atomics
        spmm1_csr_kernel<<<(NNODES + 3) / 4, 256, 0, stream>>>(rowptr, pairs, h0, h1);
        // 4. h2 = h1 @ W2 + b2   (h1 already relu'ed)
        gemm2_kernel<false><<<(NNODES + 63) / 64, 256, 0, stream>>>(h1, W2, b2, h2);
        // 5. out = logsoftmax(spmm(h2)) — gather + fused wave softmax
        spmm2_csr_kernel<<<(NNODES + 3) / 4, 256, 0, stream>>>(rowptr, pairs, h2, out);
    } else {
        // fallback: round-1 atomic path (h2 must not alias h0 here)
        float* h2f = h1 + (size_t)NNODES * NHID;
        zero_kernel<<<(NNODES * NHID / 4 + 255) / 256, 256, 0, stream>>>(
            (float4*)h1, NNODES * NHID / 4);
        spmm1_atomic_kernel<<<NEDGES / 4, 256, 0, stream>>>(ei, ew, h0, h1);
        gemm2_kernel<true><<<(NNODES + 63) / 64, 256, 0, stream>>>(h1, W2, b2, h2f);
        zero_kernel<<<(NNODES * NCLASS / 4 + 255) / 256, 256, 0, stream>>>(
            (float4*)out, NNODES * NCLASS / 4);
        spmm2_atomic_kernel<<<(NEDGES / 256) * NCLASS, 256, 0, stream>>>(ei, ew, h2f, out);
        logsoftmax_kernel<<<NNODES / 4, 256, 0, stream>>>(out);
    }
}

// Round 3
// 1242.540 us; speedup vs baseline: 9.3102x; 1.1611x over previous
//
#include <hip/hip_runtime.h>
#include <math.h>

#define NNODES 100000
#define NEDGES 3200000
#define NFEAT  512
#define NHID   256
#define NCLASS 40
#define NB_SCAN 98              // ceil(NNODES / 1024)

typedef short  bf16x8 __attribute__((ext_vector_type(8)));
typedef unsigned short u16x8 __attribute__((ext_vector_type(8)));
typedef float  f32x4  __attribute__((ext_vector_type(4)));

__device__ inline unsigned short f2bf_rne(float f) {
    unsigned u = __float_as_uint(f);
    unsigned r = (u + 0x7FFFu + ((u >> 16) & 1u)) >> 16;
    return (unsigned short)r;
}
__device__ inline float bf2f(unsigned short h) {
    return __uint_as_float((unsigned)h << 16);
}

// ============ W1 transpose + hi/lo bf16 split: W1[512][256] -> W1T[256][512]
__global__ __launch_bounds__(256) void w1_split_kernel(
    const float* __restrict__ W1, unsigned short* __restrict__ hi,
    unsigned short* __restrict__ lo)
{
    const int i = blockIdx.x * 256 + threadIdx.x;     // 131072 total
    if (i >= NFEAT * NHID) return;
    const int k = i >> 8;        // row of W1 (K)
    const int n = i & 255;       // col of W1 (N)
    const float f = W1[i];
    const unsigned short h = f2bf_rne(f);
    const unsigned short l = f2bf_rne(f - bf2f(h));
    hi[n * NFEAT + k] = h;
    lo[n * NFEAT + k] = l;
}

// ============ GEMM1 via MFMA: h0 = x @ W1 + b1 ==============================
// block = 256 thr = 4 waves; tile 64 rows x 256 cols; wave w owns cols w*64..+63
// A (x) staged fp32->bf16 hi/lo in LDS; B read directly from W1T_hi/lo (global,
// L2-resident). 16x16x32 bf16 MFMA; 3 passes (hh, hl, lh) for ~fp32 accuracy.
__global__ __launch_bounds__(256) void gemm1_mfma_kernel(
    const float* __restrict__ x, const unsigned short* __restrict__ Bhi,
    const unsigned short* __restrict__ Blo, const float* __restrict__ b1,
    float* __restrict__ h0)
{
    __shared__ __align__(16) unsigned short As_hi[64 * 40];  // [row][k], pad 40
    __shared__ __align__(16) unsigned short As_lo[64 * 40];
    const int t = threadIdx.x;
    const int lane = t & 63;
    const int w = t >> 6;
    const int row0 = blockIdx.x * 64;
    const int wn0 = w * 64;
    const int fr = lane & 15;        // fragment row/col index
    const int fq = lane >> 4;        // k-group
    // staging assignment: thread stages 8 k's of one row
    const int srow = t >> 2;             // 0..63
    const int skq  = (t & 3) * 8;        // 0,8,16,24
    const int grow = row0 + srow;
    const float* xp = x + (size_t)grow * NFEAT + skq;
    unsigned short* ah = &As_hi[srow * 40 + skq];
    unsigned short* al = &As_lo[srow * 40 + skq];

    f32x4 acc[4][4] = {};

    for (int k0 = 0; k0 < NFEAT; k0 += 32) {
        // ---- load + convert A slice (8 floats) ----
        float v[8];
        if (grow < NNODES) {
            const float4 u0 = *(const float4*)(xp + k0);
            const float4 u1 = *(const float4*)(xp + k0 + 4);
            v[0] = u0.x; v[1] = u0.y; v[2] = u0.z; v[3] = u0.w;
            v[4] = u1.x; v[5] = u1.y; v[6] = u1.z; v[7] = u1.w;
        } else {
            #pragma unroll
            for (int j = 0; j < 8; ++j) v[j] = 0.f;
        }
        u16x8 hv, lv;
        #pragma unroll
        for (int j = 0; j < 8; ++j) {
            const unsigned short h = f2bf_rne(v[j]);
            hv[j] = h;
            lv[j] = f2bf_rne(v[j] - bf2f(h));
        }
        __syncthreads();                 // prior iteration's frag reads done
        *(u16x8*)ah = hv;
        *(u16x8*)al = lv;
        __syncthreads();                 // LDS tile ready

        // ---- A frags from LDS ----
        bf16x8 a_h[4], a_l[4];
        #pragma unroll
        for (int mt = 0; mt < 4; ++mt) {
            const int off = (mt * 16 + fr) * 40 + fq * 8;
            a_h[mt] = *(const bf16x8*)&As_hi[off];
            a_l[mt] = *(const bf16x8*)&As_lo[off];
        }
        // ---- B frags direct from global (hot in L2) ----
        bf16x8 b_h[4], b_l[4];
        #pragma unroll
        for (int nt = 0; nt < 4; ++nt) {
            const int n = wn0 + nt * 16 + fr;
            const size_t boff = (size_t)n * NFEAT + k0 + fq * 8;
            b_h[nt] = *(const bf16x8*)(Bhi + boff);
            b_l[nt] = *(const bf16x8*)(Blo + boff);
        }
        // ---- MFMAs: hh + hl + lh ----
        #pragma unroll
        for (int mt = 0; mt < 4; ++mt)
            #pragma unroll
            for (int nt = 0; nt < 4; ++nt) {
                acc[mt][nt] = __builtin_amdgcn_mfma_f32_16x16x32_bf16(
                    a_h[mt], b_h[nt], acc[mt][nt], 0, 0, 0);
                acc[mt][nt] = __builtin_amdgcn_mfma_f32_16x16x32_bf16(
                    a_h[mt], b_l[nt], acc[mt][nt], 0, 0, 0);
                acc[mt][nt] = __builtin_amdgcn_mfma_f32_16x16x32_bf16(
                    a_l[mt], b_h[nt], acc[mt][nt], 0, 0, 0);
            }
    }
    // ---- epilogue: C/D layout col = lane&15, row = (lane>>4)*4 + r ----
    #pragma unroll
    for (int mt = 0; mt < 4; ++mt)
        #pragma unroll
        for (int nt = 0; nt < 4; ++nt) {
            const int c = wn0 + nt * 16 + fr;
            const float bias = b1[c];
            const int r0 = row0 + mt * 16 + fq * 4;
            #pragma unroll
            for (int r = 0; r < 4; ++r) {
                const int row = r0 + r;
                if (row < NNODES)
                    h0[(size_t)row * NHID + c] = acc[mt][nt][r] + bias;
            }
        }
}

// ============ GEMM2: h2 = h1 @ W2 + b2  [N,256] x [256,40] ==================
__global__ __launch_bounds__(256) void gemm2_kernel(
    const float* __restrict__ h1, const float* __restrict__ W2,
    const float* __restrict__ b2, float* __restrict__ h2)
{
    __shared__ float Bs[NHID * NCLASS]; // full W2: 40 KB
    __shared__ float As[64][33];
    const int t = threadIdx.x;
    const int row0 = blockIdx.x * 64;
    for (int i = t; i < NHID * NCLASS; i += 256) Bs[i] = W2[i];
    const int r  = t & 63;
    const int cg = (t >> 6) * 10;
    const int am = t >> 2, ak = (t & 3) * 8;
    float acc[10] = {};
    for (int k0 = 0; k0 < NHID; k0 += 32) {
        __syncthreads();
        float4 v0 = make_float4(0.f,0.f,0.f,0.f), v1 = v0;
        const int arow = row0 + am;
        if (arow < NNODES) {
            v0 = *(const float4*)(h1 + (size_t)arow * NHID + k0 + ak);
            v1 = *(const float4*)(h1 + (size_t)arow * NHID + k0 + ak + 4);
        }
        As[am][ak + 0] = v0.x; As[am][ak + 1] = v0.y;
        As[am][ak + 2] = v0.z; As[am][ak + 3] = v0.w;
        As[am][ak + 4] = v1.x; As[am][ak + 5] = v1.y;
        As[am][ak + 6] = v1.z; As[am][ak + 7] = v1.w;
        __syncthreads();
        #pragma unroll
        for (int k = 0; k < 32; ++k) {
            const float a = As[r][k];
            #pragma unroll
            for (int j = 0; j < 10; ++j)
                acc[j] += a * Bs[(k0 + k) * NCLASS + cg + j];
        }
    }
    const int arow = row0 + r;
    if (arow < NNODES) {
        #pragma unroll
        for (int j = 0; j < 10; ++j)
            h2[(size_t)arow * NCLASS + cg + j] = acc[j] + b2[cg + j];
    }
}

// ============ CSR build =====================================================
__global__ __launch_bounds__(256) void zero_int_kernel(int* __restrict__ p, int n)
{
    const int i = blockIdx.x * 256 + threadIdx.x;
    if (i < n) p[i] = 0;
}

__global__ __launch_bounds__(256) void hist_kernel(
    const int* __restrict__ ei, int* __restrict__ deg)
{
    const int e = blockIdx.x * 256 + threadIdx.x;
    if (e < NEDGES) atomicAdd(&deg[ei[e]], 1);
}

__global__ __launch_bounds__(256) void scan1_kernel(
    const int* __restrict__ deg, int* __restrict__ rowptr, int* __restrict__ bsum)
{
    __shared__ int s[256];
    const int b = blockIdx.x, t = threadIdx.x;
    const int i0 = b * 1024 + t * 4;
    int v[4];
    #pragma unroll
    for (int j = 0; j < 4; ++j) v[j] = (i0 + j < NNODES) ? deg[i0 + j] : 0;
    const int mysum = v[0] + v[1] + v[2] + v[3];
    s[t] = mysum;
    __syncthreads();
    for (int o = 1; o < 256; o <<= 1) {
        const int u = (t >= o) ? s[t - o] : 0;
        __syncthreads();
        s[t] += u;
        __syncthreads();
    }
    int run = s[t] - mysum;
    #pragma unroll
    for (int j = 0; j < 4; ++j) {
        if (i0 + j < NNODES) rowptr[i0 + j] = run;
        run += v[j];
    }
    if (t == 255) bsum[b] = s[255];
}

__global__ __launch_bounds__(128) void scan2_kernel(int* __restrict__ bsum)
{
    __shared__ int s[128];
    const int t = threadIdx.x;
    const int v = (t < NB_SCAN) ? bsum[t] : 0;
    s[t] = v;
    __syncthreads();
    for (int o = 1; o < 128; o <<= 1) {
        const int u = (t >= o) ? s[t - o] : 0;
        __syncthreads();
        s[t] += u;
        __syncthreads();
    }
    if (t < NB_SCAN) bsum[t] = s[t] - v;
}

__global__ __launch_bounds__(256) void scan3_kernel(
    int* __restrict__ rowptr, int* __restrict__ cursor, const int* __restrict__ bsum)
{
    const int b = blockIdx.x, t = threadIdx.x;
    const int i0 = b * 1024 + t * 4;
    const int off = bsum[b];
    #pragma unroll
    for (int j = 0; j < 4; ++j) {
        const int i = i0 + j;
        if (i < NNODES) {
            const int r = rowptr[i] + off;
            rowptr[i] = r;
            cursor[i] = r;
        }
    }
    if (b == 0 && t == 0) rowptr[NNODES] = NEDGES;
}

__global__ __launch_bounds__(256) void scatter_kernel(
    const int* __restrict__ ei, const float* __restrict__ ew,
    int* __restrict__ cursor, int2* __restrict__ pairs)
{
    const int e = blockIdx.x * 256 + threadIdx.x;
    if (e < NEDGES) {
        const int dst = ei[e];
        const int p = atomicAdd(&cursor[dst], 1);
        int2 pr;
        pr.x = ei[NEDGES + e];
        pr.y = __float_as_int(ew[e]);
        pairs[p] = pr;
    }
}

// ============ SpMM1 feature-halved (+fused ReLU): half-wave per dst =========
// pass p covers features [p*128, p*128+128); working set = 51 MB -> L3-resident
__global__ __launch_bounds__(256) void spmm1_half_kernel(
    const int* __restrict__ rowptr, const int2* __restrict__ pairs,
    const float* __restrict__ h0, float* __restrict__ h1, int p)
{
    const int dst = blockIdx.x * 8 + (threadIdx.x >> 5);
    const int hl  = threadIdx.x & 31;
    if (dst >= NNODES) return;
    const int beg = rowptr[dst], end = rowptr[dst + 1];
    const float* base = h0 + p * 128 + hl * 4;
    float4 a0 = make_float4(0.f, 0.f, 0.f, 0.f);
    float4 a1 = make_float4(0.f, 0.f, 0.f, 0.f);
    int j = beg;
    for (; j + 1 < end; j += 2) {
        const int2 p0 = pairs[j];
        const int2 p1 = pairs[j + 1];
        const float4 v0 = *(const float4*)(base + (size_t)p0.x * NHID);
        const float4 v1 = *(const float4*)(base + (size_t)p1.x * NHID);
        const float w0 = __int_as_float(p0.y), w1 = __int_as_float(p1.y);
        a0.x = fmaf(v0.x, w0, a0.x); a0.y = fmaf(v0.y, w0, a0.y);
        a0.z = fmaf(v0.z, w0, a0.z); a0.w = fmaf(v0.w, w0, a0.w);
        a1.x = fmaf(v1.x, w1, a1.x); a1.y = fmaf(v1.y, w1, a1.y);
        a1.z = fmaf(v1.z, w1, a1.z); a1.w = fmaf(v1.w, w1, a1.w);
    }
    if (j < end) {
        const int2 p0 = pairs[j];
        const float4 v0 = *(const float4*)(base + (size_t)p0.x * NHID);
        const float w0 = __int_as_float(p0.y);
        a0.x = fmaf(v0.x, w0, a0.x); a0.y = fmaf(v0.y, w0, a0.y);
        a0.z = fmaf(v0.z, w0, a0.z); a0.w = fmaf(v0.w, w0, a0.w);
    }
    float4 o;
    o.x = fmaxf(a0.x + a1.x, 0.f);
    o.y = fmaxf(a0.y + a1.y, 0.f);
    o.z = fmaxf(a0.z + a1.z, 0.f);
    o.w = fmaxf(a0.w + a1.w, 0.f);
    *(float4*)(h1 + (size_t)dst * NHID + p * 128 + hl * 4) = o;
}

// ============ SpMM2 + fused log-softmax: wave per dst =======================
__global__ __launch_bounds__(256) void spmm2_csr_kernel(
    const int* __restrict__ rowptr, const int2* __restrict__ pairs,
    const float* __restrict__ h2, float* __restrict__ out)
{
    const int dst  = blockIdx.x * 4 + (threadIdx.x >> 6);
    const int lane = threadIdx.x & 63;
    if (dst >= NNODES) return;
    const int beg = rowptr[dst], end = rowptr[dst + 1];
    float a0 = 0.f, a1 = 0.f;
    int j = beg;
    for (; j + 1 < end; j += 2) {
        const int2 p0 = pairs[j];
        const int2 p1 = pairs[j + 1];
        float v0 = 0.f, v1 = 0.f;
        if (lane < NCLASS) {
            v0 = h2[(size_t)p0.x * NCLASS + lane];
            v1 = h2[(size_t)p1.x * NCLASS + lane];
        }
        a0 = fmaf(v0, __int_as_float(p0.y), a0);
        a1 = fmaf(v1, __int_as_float(p1.y), a1);
    }
    if (j < end) {
        const int2 p0 = pairs[j];
        float v0 = 0.f;
        if (lane < NCLASS) v0 = h2[(size_t)p0.x * NCLASS + lane];
        a0 = fmaf(v0, __int_as_float(p0.y), a0);
    }
    const float acc = a0 + a1;
    float val = (lane < NCLASS) ? acc : -INFINITY;
    float m = val;
    #pragma unroll
    for (int o = 32; o >= 1; o >>= 1) m = fmaxf(m, __shfl_xor(m, o));
    float ex = (lane < NCLASS) ? expf(val - m) : 0.f;
    float s = ex;
    #pragma unroll
    for (int o = 32; o >= 1; o >>= 1) s += __shfl_xor(s, o);
    if (lane < NCLASS) out[(size_t)dst * NCLASS + lane] = val - m - logf(s);
}

// ============ launch ========================================================
extern "C" void kernel_launch(void* const* d_in, const int* in_sizes, int n_in,
                              void* d_out, int out_size, void* d_ws, size_t ws_size,
                              hipStream_t stream)
{
    const float* x  = (const float*)d_in[0];
    const int*   ei = (const int*)d_in[1];   // [2,E]: dst row then src row
    const float* ew = (const float*)d_in[2];
    const float* W1 = (const float*)d_in[3];
    const float* b1 = (const float*)d_in[4];
    const float* W2 = (const float*)d_in[5];
    const float* b2 = (const float*)d_in[6];
    float* out = (float*)d_out;

    char* ws = (char*)d_ws;
    const size_t H_BYTES = (size_t)NNODES * NHID * 4;        // 102,400,000
    float* h0 = (float*)(ws);
    float* h1 = (float*)(ws + H_BYTES);
    int2* pairs = (int2*)(ws + 2 * H_BYTES);                 // 25,600,000 B
    char* region = ws + 2 * H_BYTES + (size_t)NEDGES * 8;
    // temporal overlap: W1T (hi|lo, 512 KB) lives in region until gemm1 done;
    // rowptr/cursor/bsum (CSR) occupy the same bytes afterwards.
    int* rowptr = (int*)(region);                            // 400,016 B
    int* cursor = (int*)(region + 400032);                   // 400,000 B
    int* bsum   = (int*)(region + 800032);                   // 512 B
    unsigned short* W1T_hi = (unsigned short*)(region);           // 262,144 B
    unsigned short* W1T_lo = (unsigned short*)(region + 262144);  // 262,144 B
    float* h2 = (float*)(ws);          // aliases h0 (dead after spmm1)

    // 1. W1 -> transposed bf16 hi/lo split
    w1_split_kernel<<<(NFEAT * NHID + 255) / 256, 256, 0, stream>>>(W1, W1T_hi, W1T_lo);
    // 2. h0 = x @ W1 + b1  (MFMA, 3-pass hi/lo)
    gemm1_mfma_kernel<<<(NNODES + 63) / 64, 256, 0, stream>>>(x, W1T_hi, W1T_lo, b1, h0);
    // 3. build CSR (cursor/rowptr overwrite W1T — it's dead now)
    zero_int_kernel<<<(NNODES + 255) / 256, 256, 0, stream>>>(cursor, NNODES);
    hist_kernel<<<(NEDGES + 255) / 256, 256, 0, stream>>>(ei, cursor);
    scan1_kernel<<<NB_SCAN, 256, 0, stream>>>(cursor, rowptr, bsum);
    scan2_kernel<<<1, 128, 0, stream>>>(bsum);
    scan3_kernel<<<NB_SCAN, 256, 0, stream>>>(rowptr, cursor, bsum);
    scatter_kernel<<<(NEDGES + 255) / 256, 256, 0, stream>>>(ei, ew, cursor, pairs);
    // 4. h1 = relu(spmm(h0)) — two L3-resident feature halves
    spmm1_half_kernel<<<(NNODES + 7) / 8, 256, 0, stream>>>(rowptr, pairs, h0, h1, 0);
    spmm1_half_kernel<<<(NNODES + 7) / 8, 256, 0, stream>>>(rowptr, pairs, h0, h1, 1);
    // 5. h2 = h1 @ W2 + b2
    gemm2_kernel<<<(NNODES + 63) / 64, 256, 0, stream>>>(h1, W2, b2, h2);
    // 6. out = logsoftmax(spmm(h2))
    spmm2_csr_kernel<<<(NNODES + 3) / 4, 256, 0, stream>>>(rowptr, pairs, h2, out);
}